// Round 3
// baseline (131.268 us; speedup 1.0000x reference)
//
#include <hip/hip_runtime.h>
#include <math.h>

#define N 4096
#define E 96
#define H 6
#define DH 16
#define G 64
#define CMAX 128          // max group size supported (mean 64, std ~8 -> 128 is +8 sigma)
#define KSTR 19           // LDS row stride for qh/kh/vh (odd-ish: 2-way banks max)

// ---------------- K1: bucketing (hist+scan+scatter) + classifier fold, one block
__global__ __launch_bounds__(1024) void bucket_kernel(const int* __restrict__ grp,
                                                      int* __restrict__ counts,
                                                      int* __restrict__ offs,
                                                      int* __restrict__ bucket,
                                                      const float* __restrict__ w_out,
                                                      const float* __restrict__ b_out,
                                                      const float* __restrict__ w_cls,
                                                      const float* __restrict__ b_cls,
                                                      float* __restrict__ wf) {
    __shared__ int scount[G];
    __shared__ int soff[G];
    int t = threadIdx.x;

    // classifier fold on the top 128 threads: wf[e] = sum_u w_cls[u]*w_out[u][e]
    if (t >= 896) {
        int e = t - 896;
        if (e < E) {
            float s = 0.f;
            for (int u = 0; u < E; ++u) s += w_cls[u] * w_out[u * E + e];
            wf[e] = s;
        } else if (e == E) {
            float s = 0.f;
            for (int u = 0; u < E; ++u) s += w_cls[u] * b_out[u];
            wf[E] = s + b_cls[0];
        }
    }

    if (t < G) scount[t] = 0;
    __syncthreads();
    for (int i = t; i < N; i += 1024) atomicAdd(&scount[grp[i]], 1);
    __syncthreads();
    if (t == 0) {
        int run = 0;
        for (int g = 0; g < G; ++g) {
            soff[g] = run; offs[g] = run; counts[g] = scount[g]; run += scount[g];
        }
    }
    __syncthreads();
    for (int i = t; i < N; i += 1024) {
        int p = atomicAdd(&soff[grp[i]], 1);
        bucket[p] = i;                    // slot -> row (order within group irrelevant)
    }
}

// ---------------- K2: fused qkv + attention per (group, head)
__global__ __launch_bounds__(256) void fused_kernel(const float* __restrict__ feats,
                                                    const float* __restrict__ w_in,
                                                    const float* __restrict__ b_in,
                                                    const int* __restrict__ bucket,
                                                    const int* __restrict__ offs,
                                                    const int* __restrict__ counts,
                                                    float* __restrict__ attn_out) {
    __shared__ float wl[48 * 100];        // w_in slice: 48 cols (q,k,v x 16) x 96, stride 100
    __shared__ float qh[CMAX * KSTR];
    __shared__ float kh[CMAX * KSTR];
    __shared__ float vh[CMAX * KSTR];
    __shared__ float ps[4 * CMAX];        // per-wave softmax weights

    int g = blockIdx.x & 63;
    int h = blockIdx.x >> 6;
    int off = offs[g];
    int cnt = counts[g];
    if (cnt > CMAX) cnt = CMAX;
    if (cnt == 0) return;                 // uniform per block

    int tid = threadIdx.x, lane = tid & 63, wv = tid >> 6;

    // stage w_in slice for this head: cols part*96 + h*16 + dd, 96 floats each
    for (int idx = tid; idx < 48 * 24; idx += 256) {
        int ci = idx / 24, j = idx % 24;
        int part = ci >> 4, dd = ci & 15;
        int gcol = part * E + h * DH + dd;
        float4 w = *(const float4*)(w_in + gcol * E + j * 4);
        *(float4*)(wl + ci * 100 + j * 4) = w;
    }
    __syncthreads();

    // qkv: thread (rr = tid>>4, d = tid&15) computes q,k,v[d] for rows rr, rr+16, ...
    int d = tid & 15, rr = tid >> 4;
    float bq = b_in[h * DH + d];
    float bk = b_in[E + h * DH + d];
    float bv = b_in[2 * E + h * DH + d];
    const float4* wq = (const float4*)(wl + d * 100);
    const float4* wk = (const float4*)(wl + (16 + d) * 100);
    const float4* wvp = (const float4*)(wl + (32 + d) * 100);
    for (int rbase = 0; rbase < cnt; rbase += 16) {
        int r = rbase + rr;
        if (r < cnt) {
            int br = bucket[off + r];
            const float4* fp = (const float4*)(feats + br * E);
            float sq = 0.f, sk = 0.f, sv = 0.f;
            #pragma unroll
            for (int e4 = 0; e4 < 24; ++e4) {
                float4 f = fp[e4];
                float4 a = wq[e4], b = wk[e4], c = wvp[e4];
                sq += f.x*a.x + f.y*a.y + f.z*a.z + f.w*a.w;
                sk += f.x*b.x + f.y*b.y + f.z*b.z + f.w*b.w;
                sv += f.x*c.x + f.y*c.y + f.z*c.z + f.w*c.w;
            }
            qh[r * KSTR + d] = (sq + bq) * 0.25f;   // 1/sqrt(16)
            kh[r * KSTR + d] = sk + bk;
            vh[r * KSTR + d] = sv + bv;
        }
    }
    __syncthreads();

    // attention: wave wv handles rows r = wv, wv+4, ...
    for (int r = wv; r < cnt; r += 4) {
        float qv[16];
        #pragma unroll
        for (int e = 0; e < 16; ++e) qv[e] = qh[r * KSTR + e];   // broadcast reads

        float a0 = 0.f, a1 = 0.f;
        #pragma unroll
        for (int e = 0; e < 16; ++e) a0 += qv[e] * kh[lane * KSTR + e];
        float s0 = (lane < cnt) ? a0 : -INFINITY;
        float s1 = -INFINITY;
        if (cnt > 64) {
            #pragma unroll
            for (int e = 0; e < 16; ++e) a1 += qv[e] * kh[(64 + lane) * KSTR + e];
            s1 = (64 + lane < cnt) ? a1 : -INFINITY;
        }

        float m = fmaxf(s0, s1);
        #pragma unroll
        for (int o = 32; o >= 1; o >>= 1) m = fmaxf(m, __shfl_xor(m, o, 64));
        float p0 = __expf(s0 - m);                       // exp(-inf - m) = 0
        float p1 = (cnt > 64) ? __expf(s1 - m) : 0.f;
        float l = p0 + p1;
        #pragma unroll
        for (int o = 32; o >= 1; o >>= 1) l += __shfl_xor(l, o, 64);
        ps[wv * CMAX + lane] = p0;
        ps[wv * CMAX + 64 + lane] = p1;

        // PV: lanes (mm4 = lane>>4, dd = lane&15)
        int mm4 = lane >> 4, dd = lane & 15;
        float acc = 0.f;
        for (int m2 = mm4; m2 < cnt; m2 += 4)
            acc += ps[wv * CMAX + m2] * vh[m2 * KSTR + dd];
        acc += __shfl_xor(acc, 16, 64);
        acc += __shfl_xor(acc, 32, 64);

        if (lane < 16) {
            int i = bucket[off + r];
            attn_out[i * E + h * DH + lane] = acc / l;
        }
    }
}

// ---------------- K3: per-row dot with folded classifier + sigmoid
__global__ __launch_bounds__(256) void final_kernel(const float* __restrict__ attn_out,
                                                    const float* __restrict__ wf,
                                                    float* __restrict__ out) {
    int wid  = (blockIdx.x * blockDim.x + threadIdx.x) >> 6;
    int lane = threadIdx.x & 63;
    if (wid >= N) return;
    const float* ar = attn_out + wid * E;
    float s = ar[lane] * wf[lane];
    if (lane < E - 64) s += ar[lane + 64] * wf[lane + 64];
    #pragma unroll
    for (int o = 32; o >= 1; o >>= 1) s += __shfl_xor(s, o, 64);
    if (lane == 0) out[wid] = 1.f / (1.f + __expf(-(s + wf[E])));
}

extern "C" void kernel_launch(void* const* d_in, const int* in_sizes, int n_in,
                              void* d_out, int out_size, void* d_ws, size_t ws_size,
                              hipStream_t stream) {
    const float* feats = (const float*)d_in[0];
    const int*   grp   = (const int*)  d_in[1];
    const float* w_in  = (const float*)d_in[2];
    const float* b_in  = (const float*)d_in[3];
    const float* w_out = (const float*)d_in[4];
    const float* b_out = (const float*)d_in[5];
    const float* w_cls = (const float*)d_in[6];
    const float* b_cls = (const float*)d_in[7];
    float* out = (float*)d_out;

    float* attn = (float*)d_ws;             // N*E
    float* wf   = attn + N * E;             // 128 (96 + folded bias + pad)
    int* counts = (int*)(wf + 128);         // 64
    int* offs   = counts + 64;              // 64
    int* bucket = offs + 64;                // N

    bucket_kernel<<<1, 1024, 0, stream>>>(grp, counts, offs, bucket,
                                          w_out, b_out, w_cls, b_cls, wf);
    fused_kernel<<<G * H, 256, 0, stream>>>(feats, w_in, b_in, bucket, offs, counts, attn);
    final_kernel<<<(N * 64) / 256, 256, 0, stream>>>(attn, wf, out);
}

// Round 4
// 108.584 us; speedup vs baseline: 1.2089x; 1.2089x over previous
//
#include <hip/hip_runtime.h>
#include <math.h>

#define N 4096
#define E 96
#define H 6
#define DH 16
#define G 64
#define CMAX 128          // max supported group size (mean 64, +8 sigma safe)
#define KSTR 19           // LDS row stride: stride-19 b32 -> 2-way banks max (free)
#define NW 8              // waves per block
#define NT 512            // threads per block

// ---------------- K1: fully fused per-(group,head): bucket + qkv + attention + partial logit
__global__ __launch_bounds__(NT) void fused_kernel(const float* __restrict__ feats,
                                                   const int* __restrict__ grp,
                                                   const float* __restrict__ w_in,
                                                   const float* __restrict__ b_in,
                                                   const float* __restrict__ w_out,
                                                   const float* __restrict__ w_cls,
                                                   float* __restrict__ logit) {
    __shared__ float wl[48 * 100];        // w_in slice for this head (48 cols x 96), stride 100
    __shared__ float qh[CMAX * KSTR];
    __shared__ float kh[CMAX * KSTR];
    __shared__ float vh[CMAX * KSTR];
    __shared__ float ps[NW * CMAX];       // per-wave softmax weights
    __shared__ int   bucket[CMAX];
    __shared__ float wfh[DH];             // head slice of folded classifier
    __shared__ int   scnt;

    int g = blockIdx.x & 63;
    int h = blockIdx.x >> 6;
    int tid = threadIdx.x, lane = tid & 63, wv = tid >> 6;

    if (tid == 0) scnt = 0;
    __syncthreads();

    // ---- redundant per-block bucket build (unordered compaction; order irrelevant)
    int gv[8];
    #pragma unroll
    for (int c8 = 0; c8 < 8; ++c8)
        gv[c8] = grp[((wv + NW * c8) << 6) + lane];     // coalesced, L2-hot
    #pragma unroll
    for (int c8 = 0; c8 < 8; ++c8) {
        int i = ((wv + NW * c8) << 6) + lane;
        bool mt = (gv[c8] == g);
        unsigned long long mask = __ballot(mt);
        int base = 0;
        if (lane == 0) base = atomicAdd(&scnt, __popcll(mask));
        base = __shfl(base, 0, 64);
        if (mt) {
            int pos = base + __popcll(mask & ((1ULL << lane) - 1ULL));
            if (pos < CMAX) bucket[pos] = i;
        }
    }

    // ---- stage w_in slice: cols {q,k,v} x 16 for this head, 96 floats each
    for (int idx = tid; idx < 48 * 24; idx += NT) {
        int ci = idx / 24, j = idx % 24;
        int part = ci >> 4, dd = ci & 15;
        int gcol = part * E + h * DH + dd;
        *(float4*)(wl + ci * 100 + j * 4) = *(const float4*)(w_in + gcol * E + j * 4);
    }

    // ---- head slice of folded classifier: wfh[dd] = sum_u w_cls[u]*w_out[u][h*16+dd]
    if (wv == 0) {
        int dd = lane & 15, u4 = lane >> 4;             // 4 u-groups of 24
        float s = 0.f;
        for (int u = u4 * 24; u < u4 * 24 + 24; ++u)
            s += w_cls[u] * w_out[u * E + h * DH + dd];
        s += __shfl_xor(s, 16, 64);
        s += __shfl_xor(s, 32, 64);
        if (lane < DH) wfh[lane] = s;
    }
    __syncthreads();

    int cnt = scnt; if (cnt > CMAX) cnt = CMAX;
    if (cnt == 0) return;                               // uniform

    // ---- qkv for the group's rows: thread (d = tid&15, rr = tid>>4 in 0..31)
    int d = tid & 15, rr = tid >> 4;
    float bq = b_in[h * DH + d];
    float bk = b_in[E + h * DH + d];
    float bv = b_in[2 * E + h * DH + d];
    const float4* wq  = (const float4*)(wl + d * 100);
    const float4* wk  = (const float4*)(wl + (16 + d) * 100);
    const float4* wvp = (const float4*)(wl + (32 + d) * 100);
    for (int rbase = 0; rbase < cnt; rbase += 32) {
        int r = rbase + rr;
        if (r < cnt) {
            const float4* fp = (const float4*)(feats + bucket[r] * E);
            float sq = 0.f, sk = 0.f, sv = 0.f;
            #pragma unroll
            for (int e4 = 0; e4 < 24; ++e4) {
                float4 f = fp[e4];
                float4 a = wq[e4], b = wk[e4], c = wvp[e4];
                sq += f.x*a.x + f.y*a.y + f.z*a.z + f.w*a.w;
                sk += f.x*b.x + f.y*b.y + f.z*b.z + f.w*b.w;
                sv += f.x*c.x + f.y*c.y + f.z*c.z + f.w*c.w;
            }
            qh[r * KSTR + d] = (sq + bq) * 0.25f;       // 1/sqrt(16)
            kh[r * KSTR + d] = sk + bk;
            vh[r * KSTR + d] = sv + bv;
        }
    }
    __syncthreads();

    // ---- attention rows r = wv, wv+8, ... ; exact softmax per row in one wave
    for (int r = wv; r < cnt; r += NW) {
        float qv[16];
        #pragma unroll
        for (int e = 0; e < 16; ++e) qv[e] = qh[r * KSTR + e];   // broadcast

        float a0 = 0.f;
        #pragma unroll
        for (int e = 0; e < 16; ++e) a0 += qv[e] * kh[lane * KSTR + e];
        float s0 = (lane < cnt) ? a0 : -INFINITY;
        float s1 = -INFINITY;
        if (cnt > 64) {
            float a1 = 0.f;
            #pragma unroll
            for (int e = 0; e < 16; ++e) a1 += qv[e] * kh[(64 + lane) * KSTR + e];
            s1 = (64 + lane < cnt) ? a1 : -INFINITY;
        }

        float m = fmaxf(s0, s1);
        #pragma unroll
        for (int o = 32; o >= 1; o >>= 1) m = fmaxf(m, __shfl_xor(m, o, 64));
        float p0 = __expf(s0 - m);                      // masked lanes -> exp(-inf)=0
        float p1 = (cnt > 64) ? __expf(s1 - m) : 0.f;
        float l = p0 + p1;
        #pragma unroll
        for (int o = 32; o >= 1; o >>= 1) l += __shfl_xor(l, o, 64);
        ps[wv * CMAX + lane] = p0;
        ps[wv * CMAX + 64 + lane] = p1;

        // PV: lane = (mm4 = lane>>4, dd = lane&15)
        int mm4 = lane >> 4, dd = lane & 15;
        float acc = 0.f;
        for (int m2 = mm4; m2 < cnt; m2 += 4)
            acc += ps[wv * CMAX + m2] * vh[m2 * KSTR + dd];
        acc += __shfl_xor(acc, 16, 64);
        acc += __shfl_xor(acc, 32, 64);

        // partial logit for this head: sum_d (acc/l)*wfh[d], reduce over dd in lanes 0..15
        float part = (acc / l) * wfh[dd];
        part += __shfl_xor(part, 1, 64);
        part += __shfl_xor(part, 2, 64);
        part += __shfl_xor(part, 4, 64);
        part += __shfl_xor(part, 8, 64);
        if (lane == 0) atomicAdd(&logit[bucket[r]], part);
    }
}

// ---------------- K2: bias fold + sigmoid
__global__ __launch_bounds__(1024) void sigmoid_kernel(const float* __restrict__ logit,
                                                       const float* __restrict__ w_cls,
                                                       const float* __restrict__ b_out,
                                                       const float* __restrict__ b_cls,
                                                       float* __restrict__ out) {
    __shared__ float sbias;
    int tid = threadIdx.x;
    if (tid < 64) {
        float s = w_cls[tid] * b_out[tid];
        if (tid < 32) s += w_cls[tid + 64] * b_out[tid + 64];
        #pragma unroll
        for (int o = 32; o >= 1; o >>= 1) s += __shfl_xor(s, o, 64);
        if (tid == 0) sbias = s + b_cls[0];
    }
    __syncthreads();
    int i = blockIdx.x * 1024 + tid;
    out[i] = 1.f / (1.f + __expf(-(logit[i] + sbias)));
}

extern "C" void kernel_launch(void* const* d_in, const int* in_sizes, int n_in,
                              void* d_out, int out_size, void* d_ws, size_t ws_size,
                              hipStream_t stream) {
    const float* feats = (const float*)d_in[0];
    const int*   grp   = (const int*)  d_in[1];
    const float* w_in  = (const float*)d_in[2];
    const float* b_in  = (const float*)d_in[3];
    const float* w_out = (const float*)d_in[4];
    const float* b_out = (const float*)d_in[5];
    const float* w_cls = (const float*)d_in[6];
    const float* b_cls = (const float*)d_in[7];
    float* out = (float*)d_out;

    float* logit = (float*)d_ws;            // N floats

    hipMemsetAsync(logit, 0, N * sizeof(float), stream);
    fused_kernel<<<G * H, NT, 0, stream>>>(feats, grp, w_in, b_in, w_out, w_cls, logit);
    sigmoid_kernel<<<N / 1024, 1024, 0, stream>>>(logit, w_cls, b_out, b_cls, out);
}